// Round 10
// baseline (252.292 us; speedup 1.0000x reference)
//
#include <hip/hip_runtime.h>
#include <math.h>

// LieBatchNormSPD on MI355X — round 11: use the occupancy the trim earned.
// Round-10 post-mortem: spill GONE (VGPR=124 real, FETCH 32.8MB = one X read,
// WRITE clean), 251us total. But VGPR=124 fits 4 waves/SIMD and we launch
// only 2 blocks/CU (occupancy 14.6%) — the deg-15 trim earned headroom that
// rounds 8-9 tried to force via bounds (and spilled). Still latency-bound
// (VALUBusy 43 + MfmaUtil 18 = 60% issue, 40% stalls) => TLP pays now.
// Change: GB=1024 (4 blocks/CU, 4 matrices/wave contiguous). NOTHING else —
// launch_bounds stays (256,2) (a minimum, not a cap) so regalloc is
// untouched. LDS: k_karcher 18.4KB x 4 = 73.7KB < 160KB OK.

#define NM 32
#define PAD 36
#define WCNT 4
#define EXP_DEG 10

typedef _Float16 v8h __attribute__((ext_vector_type(8)));
typedef float v16f __attribute__((ext_vector_type(16)));
typedef unsigned int uint2v __attribute__((ext_vector_type(2)));
#define MFMA(a, b, c) __builtin_amdgcn_mfma_f32_32x32x16_f16((a), (b), (c), 0, 0, 0)

struct Frag4 { v8h h1, l1, h2, l2; };
struct Frag2 { v8h h1, h2; };

// ---------------------------------------------------------------------------
__device__ __forceinline__ void cvt_split(const float (&v)[8], v8h& hi, v8h& lo)
{
#pragma unroll
  for (int i = 0; i < 8; ++i) {
    _Float16 h = (_Float16)v[i];
    hi[i] = h;
    lo[i] = (_Float16)(v[i] - (float)h);
  }
}

__device__ __forceinline__ v8h cvt_hi(const float (&v)[8])
{
  v8h hi;
#pragma unroll
  for (int i = 0; i < 8; ++i) hi[i] = (_Float16)v[i];
  return hi;
}

__device__ __forceinline__ Frag4 split_frag(const float (&v1)[8], const float (&v2)[8])
{
  Frag4 f;
  cvt_split(v1, f.h1, f.l1);
  cvt_split(v2, f.h2, f.l2);
  return f;
}

// Full split product: acc += A*B, both operands hi+lo (drops lo*lo). 6 MFMA.
__device__ __forceinline__ v16f prodAB(const Frag4& A, const Frag4& B, v16f acc)
{
  acc = MFMA(A.h1, B.h1, acc);
  acc = MFMA(A.h2, B.h2, acc);
  acc = MFMA(A.h1, B.l1, acc);
  acc = MFMA(A.h2, B.l2, acc);
  acc = MFMA(A.l1, B.h1, acc);
  acc = MFMA(A.l2, B.h2, acc);
  return acc;
}

// A full x B hi-part-of-Frag4: 4 MFMA (drops A.h*B.l)
__device__ __forceinline__ v16f prodAH(const Frag4& A, const Frag4& B, v16f acc)
{
  acc = MFMA(A.h1, B.h1, acc);
  acc = MFMA(A.h2, B.h2, acc);
  acc = MFMA(A.l1, B.h1, acc);
  acc = MFMA(A.l2, B.h2, acc);
  return acc;
}

// A full x B hi (Frag2): 4 MFMA
__device__ __forceinline__ v16f prodAB2(const Frag4& A, const Frag2& B, v16f acc)
{
  acc = MFMA(A.h1, B.h1, acc);
  acc = MFMA(A.h2, B.h2, acc);
  acc = MFMA(A.l1, B.h1, acc);
  acc = MFMA(A.l2, B.h2, acc);
  return acc;
}

// hi x hi: 2 MFMA (small-weight terms)
__device__ __forceinline__ v16f prodHH(const Frag2& A, const Frag2& B, v16f acc)
{
  acc = MFMA(A.h1, B.h1, acc);
  acc = MFMA(A.h2, B.h2, acc);
  return acc;
}

// Exchange halves across the lane<32 / lane>=32 split (single VALU op).
__device__ __forceinline__ void plswap32(float& a, float& b)
{
  uint2v r = __builtin_amdgcn_permlane32_swap(
      __float_as_uint(a), __float_as_uint(b), false, false);
  a = __uint_as_float(r[0]);
  b = __uint_as_float(r[1]);
}

// Build B-frag fp32 values (column lane&31, k-ordered) from a C-layout reg set.
__device__ __forceinline__ void gather16(const float (&y)[16], bool /*lower*/,
                                         float (&v1)[8], float (&v2)[8])
{
#pragma unroll
  for (int i = 0; i < 4; ++i) {
    float a = y[i], b = y[4 + i];
    plswap32(a, b);
    v1[i] = a; v1[4 + i] = b;
    float p = y[8 + i], q = y[12 + i];
    plswap32(p, q);
    v2[i] = p; v2[4 + i] = q;
  }
}

__device__ __forceinline__ Frag4 frag_full(const float (&Cc)[16], bool lower)
{
  float v1[8], v2[8];
  gather16(Cc, lower, v1, v2);
  return split_frag(v1, v2);
}

__device__ __forceinline__ Frag2 frag_hi(const float (&Cc)[16], bool lower)
{
  float v1[8], v2[8];
  gather16(Cc, lower, v1, v2);
  Frag2 f;
  f.h1 = cvt_hi(v1);
  f.h2 = cvt_hi(v2);
  return f;
}

// Resident small-matrix fragments: rows of T (row-major 32x32 global).
__device__ __forceinline__ Frag4 load_T(const float* __restrict__ T, int l)
{
  const int c = l & 31, k0 = 8 * (l >> 5);
  float a1[8], a2[8];
  const float4 t0 = *(const float4*)(T + c * 32 + k0);
  const float4 t1 = *(const float4*)(T + c * 32 + k0 + 4);
  const float4 t2 = *(const float4*)(T + c * 32 + 16 + k0);
  const float4 t3 = *(const float4*)(T + c * 32 + 16 + k0 + 4);
  a1[0] = t0.x; a1[1] = t0.y; a1[2] = t0.z; a1[3] = t0.w;
  a1[4] = t1.x; a1[5] = t1.y; a1[6] = t1.z; a1[7] = t1.w;
  a2[0] = t2.x; a2[1] = t2.y; a2[2] = t2.z; a2[3] = t2.w;
  a2[4] = t3.x; a2[5] = t3.y; a2[6] = t3.z; a2[7] = t3.w;
  return split_frag(a1, a2);
}

// ---------------------------------------------------------------------------
// M = logm(T X T^T) via deg-15 two-level Chebyshev PS, C-layout registers.
// x-hat = (TXT^T - 2.55 I)/2.25. W = T4(x-hat).
// p = G0(W) + U*[G1 - G3 + 2 T2*G3](W) + T2*G2(W), G_i deg-3 in W.
__device__ __forceinline__ void log_chain(const float* __restrict__ Xb, const Frag4& tf,
                                          const float (&dsel)[16], bool lower, int l,
                                          float (&Mc)[16])
{
  const int c = l & 31, k0 = 8 * (l >> 5);
  float a1[8], a2[8];
  {
    const float4 t0 = *(const float4*)(Xb + c * 32 + k0);
    const float4 t1 = *(const float4*)(Xb + c * 32 + k0 + 4);
    const float4 t2 = *(const float4*)(Xb + c * 32 + 16 + k0);
    const float4 t3 = *(const float4*)(Xb + c * 32 + 16 + k0 + 4);
    a1[0] = t0.x; a1[1] = t0.y; a1[2] = t0.z; a1[3] = t0.w;
    a1[4] = t1.x; a1[5] = t1.y; a1[6] = t1.z; a1[7] = t1.w;
    a2[0] = t2.x; a2[1] = t2.y; a2[2] = t2.z; a2[3] = t2.w;
    a2[4] = t3.x; a2[5] = t3.y; a2[6] = t3.z; a2[7] = t3.w;
  }
  Frag4 xf = split_frag(a1, a2);
  v16f acc;
#pragma unroll
  for (int g = 0; g < 16; ++g) acc[g] = 0.f;
  acc = prodAB(xf, tf, acc);              // H2 = X * T^T (full)
  float h2[16];
#pragma unroll
  for (int g = 0; g < 16; ++g) h2[g] = acc[g];
  Frag4 hf = frag_full(h2, lower);
  v16f wxv;
#pragma unroll
  for (int g = 0; g < 16; ++g) wxv[g] = 0.f;
  wxv = prodAB(tf, hf, wxv);              // WX = T X T^T (full)
  float Uc[16];
#pragma unroll
  for (int g = 0; g < 16; ++g) Uc[g] = fmaf(0.44444444f, (float)wxv[g], -1.1333333f * dsel[g]);
  Frag4 uf = frag_full(Uc, lower);
  // T2 = 2 U^2 - I  (B hi)
  v16f u2v;
#pragma unroll
  for (int g = 0; g < 16; ++g) u2v[g] = 0.f;
  u2v = prodAH(uf, uf, u2v);
  float T2c[16];
#pragma unroll
  for (int g = 0; g < 16; ++g) T2c[g] = fmaf(2.f, (float)u2v[g], -dsel[g]);
  Frag4 t2f = frag_full(T2c, lower);
  // W = T4(U) = 2 T2^2 - I  (B hi)
  v16f wvv;
#pragma unroll
  for (int g = 0; g < 16; ++g) wvv[g] = 0.f;
  wvv = prodAH(t2f, t2f, wvv);
  float Wc[16];
#pragma unroll
  for (int g = 0; g < 16; ++g) Wc[g] = fmaf(2.f, (float)wvv[g], -dsel[g]);
  Frag2 wf = frag_hi(Wc, lower);
  // T2(W) = 2 W^2 - I   (hi-only)
  v16f x2;
#pragma unroll
  for (int g = 0; g < 16; ++g) x2[g] = 0.f;
  x2 = prodHH(wf, wf, x2);
  float T2Wc[16];
#pragma unroll
  for (int g = 0; g < 16; ++g) T2Wc[g] = fmaf(2.f, (float)x2[g], -dsel[g]);
  Frag2 t2wf = frag_hi(T2Wc, lower);
  // T3(W) = 2 W T2(W) - W  (hi-only)
  v16f x3;
#pragma unroll
  for (int g = 0; g < 16; ++g) x3[g] = 0.f;
  x3 = prodHH(wf, t2wf, x3);
  float T3Wc[16];
#pragma unroll
  for (int g = 0; g < 16; ++g) T3Wc[g] = fmaf(2.f, (float)x3[g], -Wc[g]);
  // G_i combos, deg-3 in W (T4W/T5W truncated: combined weight <=1.1e-4)
  float G0c[16], G1c[16], G2c[16], G3c[16];
#pragma unroll
  for (int g = 0; g < 16; ++g) {
    G0c[g] = fmaf(-0.0648f, Wc[g], fmaf(-4.1990400e-3f, T2Wc[g],
              fmaf(-3.6279706e-4f, T3Wc[g], 0.62860866f * dsel[g])));
    G1c[g] = fmaf(6.1281955e-2f, Wc[g], fmaf(4.3920473e-3f, T2Wc[g],
              fmaf(3.9321735e-4f, T3Wc[g], 1.1941979f * dsel[g])));
    G2c[g] = fmaf(-2.8889075e-2f, Wc[g], fmaf(-2.2149252e-3f, T2Wc[g],
              fmaf(-2.0372185e-4f, T3Wc[g], -0.34555546f * dsel[g])));
    G3c[g] = fmaf(1.1604296e-2f, Wc[g], fmaf(9.2604467e-4f, T2Wc[g],
              fmaf(8.6928673e-5f, T3Wc[g], 0.11335902f * dsel[g])));
  }
  // Q = G1 - G3 + 2 T2*G3  (G3 hi: |G3| <= ~0.12)
  v16f qv;
#pragma unroll
  for (int g = 0; g < 16; ++g) qv[g] = 0.5f * (G1c[g] - G3c[g]);
  Frag2 g3fh = frag_hi(G3c, lower);
  qv = prodAB2(t2f, g3fh, qv);
  float Qc[16];
#pragma unroll
  for (int g = 0; g < 16; ++g) Qc[g] = 2.f * (float)qv[g];
  Frag4 qf = frag_full(Qc, lower);        // Q ~ O(1.2): keep full
  // p = G0 + U*Q + T2*G2   (G2 hi: |G2| <= ~0.35)
  v16f r;
#pragma unroll
  for (int g = 0; g < 16; ++g) r[g] = G0c[g];
  r = prodAB(uf, qf, r);
  Frag2 g2fh = frag_hi(G2c, lower);
  r = prodAB2(t2f, g2fh, r);
#pragma unroll
  for (int g = 0; g < 16; ++g) Mc[g] = r[g];
}

// W = Lw * expm(Fc) * Lw^T via PS (q=4, deg 10 Taylor), C-layout registers.
__device__ __forceinline__ void exp_apply(const float (&Fc)[16], const Frag4& tw,
                                          const float (&dsel)[16], bool lower,
                                          float (&Wc)[16])
{
  Frag4 ff = frag_full(Fc, lower);
  v16f p2;
#pragma unroll
  for (int g = 0; g < 16; ++g) p2[g] = 0.f;
  p2 = prodAB(ff, ff, p2);                // F2 (full: feeds 0.5 coeff + F3/F4)
  float F2c[16];
#pragma unroll
  for (int g = 0; g < 16; ++g) F2c[g] = p2[g];
  Frag4 f2f = frag_full(F2c, lower);
  v16f p3;
#pragma unroll
  for (int g = 0; g < 16; ++g) p3[g] = 0.f;
  p3 = prodAH(ff, f2f, p3);               // F3 (coeff <=1/6: B hi)
  float F3c[16];
#pragma unroll
  for (int g = 0; g < 16; ++g) F3c[g] = p3[g];
  v16f p4;
#pragma unroll
  for (int g = 0; g < 16; ++g) p4[g] = 0.f;
  p4 = prodAH(f2f, f2f, p4);              // F4 (coeff <=1/24: B hi)
  float F4c[16];
#pragma unroll
  for (int g = 0; g < 16; ++g) F4c[g] = p4[g];
  Frag2 f4fh = frag_hi(F4c, lower);       // F4 only ever used hi
  // P = I/8! + F/9! + F2/10!
  float Pc[16];
#pragma unroll
  for (int g = 0; g < 16; ++g)
    Pc[g] = fmaf(2.7557319e-7f, F2c[g], fmaf(2.7557319e-6f, Fc[g], 2.4801587e-5f * dsel[g]));
  Frag2 pf = frag_hi(Pc, lower);
  // Q = (I/4! + F/5! + F2/6! + F3/7!) + F4*P
  v16f q;
#pragma unroll
  for (int g = 0; g < 16; ++g)
    q[g] = fmaf(1.9841270e-4f, F3c[g],
            fmaf(1.3888889e-3f, F2c[g], fmaf(8.3333333e-3f, Fc[g], 4.1666667e-2f * dsel[g])));
  q = prodHH(f4fh, pf, q);
  float Qc[16];
#pragma unroll
  for (int g = 0; g < 16; ++g) Qc[g] = q[g];
  Frag2 qf = frag_hi(Qc, lower);
  // S = (I + F + F2/2 + F3/6) + F4*Q
  v16f s;
#pragma unroll
  for (int g = 0; g < 16; ++g)
    s[g] = fmaf(0.16666667f, F3c[g], fmaf(0.5f, F2c[g], Fc[g] + dsel[g]));
  s = prodHH(f4fh, qf, s);
  float Sc[16];
#pragma unroll
  for (int g = 0; g < 16; ++g) Sc[g] = s[g];
  // H2 = S * Lw^T ; W = Lw * H2  (full: direct output path)
  Frag4 sf = frag_full(Sc, lower);
  v16f h;
#pragma unroll
  for (int g = 0; g < 16; ++g) h[g] = 0.f;
  h = prodAB(sf, tw, h);
  float h2[16];
#pragma unroll
  for (int g = 0; g < 16; ++g) h2[g] = h[g];
  Frag4 hf = frag_full(h2, lower);
  v16f wv;
#pragma unroll
  for (int g = 0; g < 16; ++g) wv[g] = 0.f;
  wv = prodAB(tw, hf, wv);
#pragma unroll
  for (int g = 0; g < 16; ++g) Wc[g] = wv[g];
}

// ---------------------------------------------------------------------------
// y <- A*y + ck*I  (single-wave helper kernels)
__device__ __forceinline__ void horner_step(const Frag4& af, float (&y)[16], float ck,
                                            const float (&dsel)[16], bool lower)
{
  float v1[8], v2[8];
  gather16(y, lower, v1, v2);
  Frag4 yf = split_frag(v1, v2);
  v16f a;
#pragma unroll
  for (int g = 0; g < 16; ++g) a[g] = ck * dsel[g];
  a = prodAB(af, yf, a);
#pragma unroll
  for (int g = 0; g < 16; ++g) y[g] = a[g];
}

__device__ __forceinline__ void load_Cmat(const float* __restrict__ g, float scale,
                                          int c, int rb, float (&Cc)[16])
{
#pragma unroll
  for (int q = 0; q < 4; ++q)
#pragma unroll
    for (int d = 0; d < 4; ++d)
      Cc[4 * q + d] = g[(8 * q + rb + d) * NM + c] * scale;
}

// Fused dual Cholesky (64 threads)
__device__ void chol32x2(float* A1, float* L1, float* A2, float* L2)
{
  const int t = threadIdx.x;
  for (int e = t; e < NM * PAD; e += 64) { L1[e] = 0.f; L2[e] = 0.f; }
  __syncthreads();
#pragma unroll 1
  for (int k = 0; k < NM; ++k) {
    const float r1 = rsqrtf(A1[k * PAD + k]);
    const float r2 = rsqrtf(A2[k * PAD + k]);
    if (t >= k && t < NM) {
      L1[t * PAD + k] = A1[t * PAD + k] * r1;
      L2[t * PAD + k] = A2[t * PAD + k] * r2;
    }
    __syncthreads();
    const int j = k + 1 + (t >> 1);
    if (j < NM) {
      const float l1 = L1[j * PAD + k], l2 = L2[j * PAD + k];
#pragma unroll 2
      for (int i = j + (t & 1); i < NM; i += 2) {
        A1[i * PAD + j] = fmaf(-L1[i * PAD + k], l1, A1[i * PAD + j]);
        A2[i * PAD + j] = fmaf(-L2[i * PAD + k], l2, A2[i * PAD + j]);
      }
    }
    __syncthreads();
  }
}

// ---------------------------------------------------------------------------
// P0: bm accumulation
__global__ __launch_bounds__(256) void k_bmsum(const float* __restrict__ X,
                                               float* __restrict__ bm_acc, int mats)
{
  const int t = threadIdx.x;
  const float* base = X + (size_t)blockIdx.x * mats * (NM * NM);
  float s0 = 0.f, s1 = 0.f, s2 = 0.f, s3 = 0.f;
  for (int b = 0; b < mats; ++b) {
    const float* Xb = base + (size_t)b * (NM * NM);
    s0 += Xb[t]; s1 += Xb[t + 256]; s2 += Xb[t + 512]; s3 += Xb[t + 768];
  }
  atomicAdd(&bm_acc[t], s0);       atomicAdd(&bm_acc[t + 256], s1);
  atomicAdd(&bm_acc[t + 512], s2); atomicAdd(&bm_acc[t + 768], s3);
}

// P0b: bm^{1/2}, bm^{-1/2}
__global__ void k_bmroot(const float* __restrict__ bm_acc, float inv_batch,
                         float* __restrict__ bm_sq_out, float* __restrict__ bm_isq_out)
{
  const int l = threadIdx.x;
  const bool lower = l < 32;
  const int c = l & 31, rb = 4 * (l >> 5);
  float dsel[16];
#pragma unroll
  for (int g = 0; g < 16; ++g) dsel[g] = ((g & 3) + 8 * (g >> 2) + rb == c) ? 1.f : 0.f;
  float bmc[16];
  load_Cmat(bm_acc, inv_batch, c, rb, bmc);
  float Ec[16];
#pragma unroll
  for (int g = 0; g < 16; ++g) Ec[g] = fmaf(0.5f, bmc[g], -dsel[g]);
  Frag4 ef = frag_full(Ec, lower);
  float y[16];
#pragma unroll
  for (int g = 0; g < 16; ++g) y[g] = fmaf(0.17619705f, Ec[g], -0.18547058f * dsel[g]);
  {
    const float bc[9] = {0.19638062f, -0.20947266f, 0.22558594f, -0.24609375f,
                         0.27343750f, -0.31250000f, 0.37500000f, -0.50000000f, 1.0f};
#pragma unroll
    for (int k = 0; k < 9; ++k) horner_step(ef, y, bc[k], dsel, lower);
  }
  const float is2 = 0.70710678f;
#pragma unroll
  for (int q = 0; q < 4; ++q)
    *(float4*)(bm_isq_out + c * NM + 8 * q + rb) =
        make_float4(y[4 * q] * is2, y[4 * q + 1] * is2,
                    y[4 * q + 2] * is2, y[4 * q + 3] * is2);
  float v1[8], v2[8];
  gather16(y, lower, v1, v2);
  Frag4 yf = split_frag(v1, v2);
  gather16(bmc, lower, v1, v2);
  Frag4 bf = split_frag(v1, v2);
  v16f a;
#pragma unroll
  for (int g = 0; g < 16; ++g) a[g] = 0.f;
  a = prodAB(bf, yf, a);
#pragma unroll
  for (int q = 0; q < 4; ++q)
    *(float4*)(bm_sq_out + c * NM + 8 * q + rb) =
        make_float4(a[4 * q] * is2, a[4 * q + 1] * is2,
                    a[4 * q + 2] * is2, a[4 * q + 3] * is2);
}

// P1: GT accumulation (contiguous per-wave chunks)
__global__ __launch_bounds__(256, 2) void k_karcher(const float* __restrict__ X,
                                                    const float* __restrict__ Sm,
                                                    float* __restrict__ gt_acc, int batch)
{
  __shared__ float red[WCNT][NM * PAD];
  const int tid = threadIdx.x, w = tid >> 6, l = tid & 63;
  const bool lower = l < 32;
  const int c = l & 31, rb = 4 * (l >> 5);
  float dsel[16];
#pragma unroll
  for (int g = 0; g < 16; ++g) dsel[g] = ((g & 3) + 8 * (g >> 2) + rb == c) ? 1.f : 0.f;
  Frag4 tf = load_T(Sm, l);
  float gt[16];
#pragma unroll
  for (int g = 0; g < 16; ++g) gt[g] = 0.f;
  const int nw = gridDim.x * WCNT;
  const int wid = blockIdx.x * WCNT + w;
  const int qq = batch / nw, rr = batch - qq * nw;
  const int cnt = qq + (wid < rr ? 1 : 0);
  const int b0 = wid * qq + (wid < rr ? wid : rr);
#pragma unroll 1
  for (int ii = 0; ii < cnt; ++ii) {
    float Mc[16];
    log_chain(X + (size_t)(b0 + ii) * (NM * NM), tf, dsel, lower, l, Mc);
#pragma unroll
    for (int g = 0; g < 16; ++g) gt[g] += Mc[g];
  }
#pragma unroll
  for (int q = 0; q < 4; ++q)
    *(float4*)(&red[w][c * PAD + 8 * q + rb]) =
        make_float4(gt[4 * q], gt[4 * q + 1], gt[4 * q + 2], gt[4 * q + 3]);
  __syncthreads();
  for (int e = tid; e < NM * NM; e += 256) {
    const int i = e >> 5, j = e & 31;
    float s = 0.f;
#pragma unroll
    for (int ww = 0; ww < WCNT; ++ww) s += red[ww][j * PAD + i];
    atomicAdd(&gt_acc[e], s);
  }
}

// P2: batch_mean = bm_sq expm(GT) bm_sq; Linv, Lw
__global__ void k_prep(const float* __restrict__ gt_acc, float inv_batch,
                       const float* __restrict__ bm_sq_g, const float* __restrict__ weight,
                       float* __restrict__ Linv_out, float* __restrict__ Lw_out)
{
  __shared__ float A1[NM * PAD], L1[NM * PAD], A2[NM * PAD], L2[NM * PAD];
  __shared__ float rd[NM];
  const int l = threadIdx.x;
  const bool lower = l < 32;
  const int c = l & 31, rb = 4 * (l >> 5);
  float dsel[16];
#pragma unroll
  for (int g = 0; g < 16; ++g) dsel[g] = ((g & 3) + 8 * (g >> 2) + rb == c) ? 1.f : 0.f;
  for (int e = l; e < NM * NM; e += 64) A2[(e >> 5) * PAD + (e & 31)] = weight[e];
  float Fc[16];
  load_Cmat(gt_acc, inv_batch, c, rb, Fc);
  Frag4 ff = frag_full(Fc, lower);
  float s[16];
#pragma unroll
  for (int g = 0; g < 16; ++g) s[g] = fmaf(2.7557319e-7f, Fc[g], 2.7557319e-6f * dsel[g]);
  {
    const float ec[9] = {2.4801587e-5f, 1.9841270e-4f, 1.3888889e-3f, 8.3333333e-3f,
                         4.1666667e-2f, 1.6666667e-1f, 0.5f, 1.f, 1.f};
#pragma unroll
    for (int k = 0; k < 9; ++k) horner_step(ff, s, ec[k], dsel, lower);
  }
  float bsc[16];
  load_Cmat(bm_sq_g, 1.f, c, rb, bsc);
  Frag4 sf = frag_full(s, lower);
  Frag4 bf = frag_full(bsc, lower);
  v16f h;
#pragma unroll
  for (int g = 0; g < 16; ++g) h[g] = 0.f;
  h = prodAB(sf, bf, h);
  float h2[16];
#pragma unroll
  for (int g = 0; g < 16; ++g) h2[g] = h[g];
  Frag4 hf = frag_full(h2, lower);
  v16f bmv;
#pragma unroll
  for (int g = 0; g < 16; ++g) bmv[g] = 0.f;
  bmv = prodAB(bf, hf, bmv);
#pragma unroll
  for (int q = 0; q < 4; ++q)
    *(float4*)(&A1[c * PAD + 8 * q + rb]) =
        make_float4(bmv[4 * q], bmv[4 * q + 1], bmv[4 * q + 2], bmv[4 * q + 3]);
  chol32x2(A1, L1, A2, L2);
  for (int e = l; e < NM * NM; e += 64) Lw_out[e] = L2[(e >> 5) * PAD + (e & 31)];
  if (l < NM) rd[l] = 1.f / L1[l * PAD + l];
  __syncthreads();
  if (l < NM) {
    float z[NM];
#pragma unroll
    for (int i = 0; i < NM; ++i) {
      float sv = (i == l) ? 1.f : 0.f;
#pragma unroll
      for (int j = 0; j < i; ++j) sv = fmaf(-L1[i * PAD + j], z[j], sv);
      z[i] = sv * rd[i];
    }
#pragma unroll
    for (int i = 0; i < NM; ++i) Linv_out[i * NM + l] = z[i];
  }
}

// P3: M = logm(Linv X Linv^T); var; optional M store (frag order)
__global__ __launch_bounds__(256, 2) void k_center(const float* __restrict__ X,
                                                   const float* __restrict__ Linv,
                                                   float* __restrict__ Mout,
                                                   float* __restrict__ var_acc,
                                                   int storeM, int batch)
{
  __shared__ float vred[WCNT];
  const int tid = threadIdx.x, w = tid >> 6, l = tid & 63;
  const bool lower = l < 32;
  const int c = l & 31, rb = 4 * (l >> 5);
  float dsel[16];
#pragma unroll
  for (int g = 0; g < 16; ++g) dsel[g] = ((g & 3) + 8 * (g >> 2) + rb == c) ? 1.f : 0.f;
  Frag4 tf = load_T(Linv, l);
  float dist = 0.f;
  const int nw = gridDim.x * WCNT;
  const int wid = blockIdx.x * WCNT + w;
  const int qq = batch / nw, rr = batch - qq * nw;
  const int cnt = qq + (wid < rr ? 1 : 0);
  const int b0 = wid * qq + (wid < rr ? wid : rr);
#pragma unroll 1
  for (int ii = 0; ii < cnt; ++ii) {
    const int b = b0 + ii;
    float Mc[16];
    log_chain(X + (size_t)b * (NM * NM), tf, dsel, lower, l, Mc);
    if (storeM) {
      float* Mb = Mout + (size_t)b * (NM * NM) + l * 16;
#pragma unroll
      for (int q = 0; q < 4; ++q)
        *(float4*)(Mb + 4 * q) =
            make_float4(Mc[4 * q], Mc[4 * q + 1], Mc[4 * q + 2], Mc[4 * q + 3]);
    }
#pragma unroll
    for (int g = 0; g < 16; ++g) dist = fmaf(Mc[g], Mc[g], dist);
  }
  for (int off = 32; off > 0; off >>= 1) dist += __shfl_down(dist, off);
  if (l == 0) vred[w] = dist;
  __syncthreads();
  if (tid == 0)
    atomicAdd(var_acc, vred[0] + vred[1] + vred[2] + vred[3]);
}

// P4: out = Lw expm(f*M) Lw^T (M from ws, frag order)
__global__ __launch_bounds__(256, 2) void k_scale(const float* __restrict__ Mi,
                                                  const float* __restrict__ Lw,
                                                  const float* __restrict__ shift,
                                                  const float* __restrict__ var_acc,
                                                  float* __restrict__ out, float invb,
                                                  int batch)
{
  const int tid = threadIdx.x, w = tid >> 6, l = tid & 63;
  const bool lower = l < 32;
  const int c = l & 31, rb = 4 * (l >> 5);
  float dsel[16];
#pragma unroll
  for (int g = 0; g < 16; ++g) dsel[g] = ((g & 3) + 8 * (g >> 2) + rb == c) ? 1.f : 0.f;
  Frag4 tw = load_T(Lw, l);
  const float fac = shift[0] / sqrtf(var_acc[0] * invb + 1e-5f);
  const int nw = gridDim.x * WCNT;
  const int wid = blockIdx.x * WCNT + w;
  const int qq = batch / nw, rr = batch - qq * nw;
  const int cnt = qq + (wid < rr ? 1 : 0);
  const int b0 = wid * qq + (wid < rr ? wid : rr);
#pragma unroll 1
  for (int ii = 0; ii < cnt; ++ii) {
    const int b = b0 + ii;
    const float* Mb = Mi + (size_t)b * (NM * NM) + l * 16;
    float Fc[16];
#pragma unroll
    for (int q = 0; q < 4; ++q) {
      const float4 m4 = *(const float4*)(Mb + 4 * q);
      Fc[4 * q] = fac * m4.x; Fc[4 * q + 1] = fac * m4.y;
      Fc[4 * q + 2] = fac * m4.z; Fc[4 * q + 3] = fac * m4.w;
    }
    float Wc[16];
    exp_apply(Fc, tw, dsel, lower, Wc);
    float* ob = out + (size_t)b * (NM * NM);
#pragma unroll
    for (int q = 0; q < 4; ++q)
      *(float4*)(ob + c * 32 + 8 * q + rb) =
          make_float4(Wc[4 * q], Wc[4 * q + 1], Wc[4 * q + 2], Wc[4 * q + 3]);
  }
}

// P4b fallback (ws too small): recompute log, then exp + output
__global__ __launch_bounds__(256, 2) void k_scale2(const float* __restrict__ X,
                                                   const float* __restrict__ Linv,
                                                   const float* __restrict__ Lw,
                                                   const float* __restrict__ shift,
                                                   const float* __restrict__ var_acc,
                                                   float* __restrict__ out, float invb,
                                                   int batch)
{
  const int tid = threadIdx.x, w = tid >> 6, l = tid & 63;
  const bool lower = l < 32;
  const int c = l & 31, rb = 4 * (l >> 5);
  float dsel[16];
#pragma unroll
  for (int g = 0; g < 16; ++g) dsel[g] = ((g & 3) + 8 * (g >> 2) + rb == c) ? 1.f : 0.f;
  Frag4 tf = load_T(Linv, l);
  Frag4 tw = load_T(Lw, l);
  const float fac = shift[0] / sqrtf(var_acc[0] * invb + 1e-5f);
  const int nw = gridDim.x * WCNT;
  const int wid = blockIdx.x * WCNT + w;
  const int qq = batch / nw, rr = batch - qq * nw;
  const int cnt = qq + (wid < rr ? 1 : 0);
  const int b0 = wid * qq + (wid < rr ? wid : rr);
#pragma unroll 1
  for (int ii = 0; ii < cnt; ++ii) {
    const int b = b0 + ii;
    float Mc[16];
    log_chain(X + (size_t)b * (NM * NM), tf, dsel, lower, l, Mc);
#pragma unroll
    for (int g = 0; g < 16; ++g) Mc[g] *= fac;
    float Wc[16];
    exp_apply(Mc, tw, dsel, lower, Wc);
    float* ob = out + (size_t)b * (NM * NM);
#pragma unroll
    for (int q = 0; q < 4; ++q)
      *(float4*)(ob + c * 32 + 8 * q + rb) =
          make_float4(Wc[4 * q], Wc[4 * q + 1], Wc[4 * q + 2], Wc[4 * q + 3]);
  }
}

// ---------------------------------------------------------------------------
extern "C" void kernel_launch(void* const* d_in, const int* in_sizes, int n_in,
                              void* d_out, int out_size, void* d_ws, size_t ws_size,
                              hipStream_t stream)
{
  const float* X = (const float*)d_in[0];
  const float* weight = (const float*)d_in[1];
  const float* shift = (const float*)d_in[2];
  float* out = (float*)d_out;
  float* W = (float*)d_ws;
  const int batch = in_sizes[0] / (NM * NM);          // 16384
  float* bm_acc = W;                                  // 1024
  float* gt_acc = W + 1024;                           // 1024
  float* var_acc = W + 2048;                          // 1 (+pad)
  float* bm_sq = W + 2304;                            // 1024
  float* bm_isq = W + 3328;                           // 1024
  float* Linv = W + 4352;                             // 1024 (row-major)
  float* Lw = W + 5376;                               // 1024 (row-major)
  float* M = W + 6400;                                // batch*1024
  const size_t needM = (size_t)(6400 + (size_t)batch * NM * NM) * sizeof(float);
  const int storeM = (ws_size >= needM) ? 1 : 0;
  const int GB = 1024;                                // 4 blocks/CU (VGPR=124 fits 4 waves/SIMD)
  const int GS = 512;                                 // bmsum grid
  const float invb = 1.f / (float)batch;

  hipMemsetAsync(W, 0, 2056 * sizeof(float), stream);

  hipLaunchKernelGGL(k_bmsum, dim3(GS), dim3(256), 0, stream, X, bm_acc, batch / GS);
  hipLaunchKernelGGL(k_bmroot, dim3(1), dim3(64), 0, stream, bm_acc, invb, bm_sq, bm_isq);
  hipLaunchKernelGGL(k_karcher, dim3(GB), dim3(256), 0, stream, X, bm_isq, gt_acc, batch);
  hipLaunchKernelGGL(k_prep, dim3(1), dim3(64), 0, stream, gt_acc, invb, bm_sq, weight, Linv, Lw);
  hipLaunchKernelGGL(k_center, dim3(GB), dim3(256), 0, stream, X, Linv, M, var_acc, storeM, batch);
  if (storeM)
    hipLaunchKernelGGL(k_scale, dim3(GB), dim3(256), 0, stream, M, Lw, shift, var_acc, out, invb, batch);
  else
    hipLaunchKernelGGL(k_scale2, dim3(GB), dim3(256), 0, stream, X, Linv, Lw, shift, var_acc, out, invb, batch);
}

// Round 11
// 247.727 us; speedup vs baseline: 1.0184x; 1.0184x over previous
//
#include <hip/hip_runtime.h>
#include <math.h>

// LieBatchNormSPD on MI355X — round 12: packed-f16 combos, cut VALU plumbing.
// Round-11 post-mortem: GB=1024 did NOT raise occupancy (15%) — the 2
// waves/SIMD cap is register-file (VGPR 124 + AGPR accumulators ~190 total),
// grid-independent. TLP closed; cut per-wave work instead. VALU:MFMA = 9:1,
// dominated by fragment plumbing + the 4x 4-term fp32 G-combos (~470 inst).
// gather16 is LINEAR => build G2/G3 fragments directly in f16 on the
// already-gathered W/T2W/T3W/I frags via packed-f16 vector math (32 inst vs
// ~88 each); G1-G3 folds into one fp32 combo for the Q init. Plus hi-B on
// U*Q and exp's S*Lw^T (analyzed <=1.5e-3, under bf16 output quantization;
// rounds 9-10 proved such trims land bit-identical). logm 38->36 MFMA,
// -240 VALU/matrix; exp 30->28. Bounds stay (256,2) — no regalloc gamble;
// watch VGPR_Count for a future occupancy-3 retry.

#define NM 32
#define PAD 36
#define WCNT 4
#define EXP_DEG 10

typedef _Float16 v8h __attribute__((ext_vector_type(8)));
typedef float v16f __attribute__((ext_vector_type(16)));
typedef unsigned int uint2v __attribute__((ext_vector_type(2)));
#define MFMA(a, b, c) __builtin_amdgcn_mfma_f32_32x32x16_f16((a), (b), (c), 0, 0, 0)

struct Frag4 { v8h h1, l1, h2, l2; };
struct Frag2 { v8h h1, h2; };

// ---------------------------------------------------------------------------
__device__ __forceinline__ void cvt_split(const float (&v)[8], v8h& hi, v8h& lo)
{
#pragma unroll
  for (int i = 0; i < 8; ++i) {
    _Float16 h = (_Float16)v[i];
    hi[i] = h;
    lo[i] = (_Float16)(v[i] - (float)h);
  }
}

__device__ __forceinline__ v8h cvt_hi(const float (&v)[8])
{
  v8h hi;
#pragma unroll
  for (int i = 0; i < 8; ++i) hi[i] = (_Float16)v[i];
  return hi;
}

__device__ __forceinline__ Frag4 split_frag(const float (&v1)[8], const float (&v2)[8])
{
  Frag4 f;
  cvt_split(v1, f.h1, f.l1);
  cvt_split(v2, f.h2, f.l2);
  return f;
}

// Full split product: acc += A*B, both operands hi+lo (drops lo*lo). 6 MFMA.
__device__ __forceinline__ v16f prodAB(const Frag4& A, const Frag4& B, v16f acc)
{
  acc = MFMA(A.h1, B.h1, acc);
  acc = MFMA(A.h2, B.h2, acc);
  acc = MFMA(A.h1, B.l1, acc);
  acc = MFMA(A.h2, B.l2, acc);
  acc = MFMA(A.l1, B.h1, acc);
  acc = MFMA(A.l2, B.h2, acc);
  return acc;
}

// A full x B hi-part-of-Frag4: 4 MFMA (drops A.h*B.l)
__device__ __forceinline__ v16f prodAH(const Frag4& A, const Frag4& B, v16f acc)
{
  acc = MFMA(A.h1, B.h1, acc);
  acc = MFMA(A.h2, B.h2, acc);
  acc = MFMA(A.l1, B.h1, acc);
  acc = MFMA(A.l2, B.h2, acc);
  return acc;
}

// A full x B hi (Frag2): 4 MFMA
__device__ __forceinline__ v16f prodAB2(const Frag4& A, const Frag2& B, v16f acc)
{
  acc = MFMA(A.h1, B.h1, acc);
  acc = MFMA(A.h2, B.h2, acc);
  acc = MFMA(A.l1, B.h1, acc);
  acc = MFMA(A.l2, B.h2, acc);
  return acc;
}

// hi x hi: 2 MFMA (small-weight terms)
__device__ __forceinline__ v16f prodHH(const Frag2& A, const Frag2& B, v16f acc)
{
  acc = MFMA(A.h1, B.h1, acc);
  acc = MFMA(A.h2, B.h2, acc);
  return acc;
}

// Exchange halves across the lane<32 / lane>=32 split (single VALU op).
__device__ __forceinline__ void plswap32(float& a, float& b)
{
  uint2v r = __builtin_amdgcn_permlane32_swap(
      __float_as_uint(a), __float_as_uint(b), false, false);
  a = __uint_as_float(r[0]);
  b = __uint_as_float(r[1]);
}

// Build B-frag fp32 values (column lane&31, k-ordered) from a C-layout reg set.
__device__ __forceinline__ void gather16(const float (&y)[16], bool /*lower*/,
                                         float (&v1)[8], float (&v2)[8])
{
#pragma unroll
  for (int i = 0; i < 4; ++i) {
    float a = y[i], b = y[4 + i];
    plswap32(a, b);
    v1[i] = a; v1[4 + i] = b;
    float p = y[8 + i], q = y[12 + i];
    plswap32(p, q);
    v2[i] = p; v2[4 + i] = q;
  }
}

__device__ __forceinline__ Frag4 frag_full(const float (&Cc)[16], bool lower)
{
  float v1[8], v2[8];
  gather16(Cc, lower, v1, v2);
  return split_frag(v1, v2);
}

__device__ __forceinline__ Frag2 frag_hi(const float (&Cc)[16], bool lower)
{
  float v1[8], v2[8];
  gather16(Cc, lower, v1, v2);
  Frag2 f;
  f.h1 = cvt_hi(v1);
  f.h2 = cvt_hi(v2);
  return f;
}

// Packed-f16 4-term combo on ALREADY-GATHERED fragments (gather is linear):
// out = c0*I + c1*A + c2*B + c3*C, all in half precision (pk_fma).
__device__ __forceinline__ Frag2 combo4h(const Frag2& If, const Frag2& A,
                                         const Frag2& B, const Frag2& C,
                                         float c0, float c1, float c2, float c3)
{
  const _Float16 h0 = (_Float16)c0, h1 = (_Float16)c1,
                 h2 = (_Float16)c2, h3 = (_Float16)c3;
  Frag2 r;
  r.h1 = If.h1 * h0 + A.h1 * h1 + B.h1 * h2 + C.h1 * h3;
  r.h2 = If.h2 * h0 + A.h2 * h1 + B.h2 * h2 + C.h2 * h3;
  return r;
}

// Resident small-matrix fragments: rows of T (row-major 32x32 global).
__device__ __forceinline__ Frag4 load_T(const float* __restrict__ T, int l)
{
  const int c = l & 31, k0 = 8 * (l >> 5);
  float a1[8], a2[8];
  const float4 t0 = *(const float4*)(T + c * 32 + k0);
  const float4 t1 = *(const float4*)(T + c * 32 + k0 + 4);
  const float4 t2 = *(const float4*)(T + c * 32 + 16 + k0);
  const float4 t3 = *(const float4*)(T + c * 32 + 16 + k0 + 4);
  a1[0] = t0.x; a1[1] = t0.y; a1[2] = t0.z; a1[3] = t0.w;
  a1[4] = t1.x; a1[5] = t1.y; a1[6] = t1.z; a1[7] = t1.w;
  a2[0] = t2.x; a2[1] = t2.y; a2[2] = t2.z; a2[3] = t2.w;
  a2[4] = t3.x; a2[5] = t3.y; a2[6] = t3.z; a2[7] = t3.w;
  return split_frag(a1, a2);
}

// ---------------------------------------------------------------------------
// M = logm(T X T^T) via deg-15 two-level Chebyshev PS, C-layout registers.
// x-hat = (TXT^T - 2.55 I)/2.25. W = T4(x-hat).
// p = G0(W) + U*[G1 - G3 + 2 T2*G3](W) + T2*G2(W), G_i deg-3 in W.
// G2/G3 built as packed-f16 fragments directly (gather linearity).
__device__ __forceinline__ void log_chain(const float* __restrict__ Xb, const Frag4& tf,
                                          const Frag2& if2,
                                          const float (&dsel)[16], bool lower, int l,
                                          float (&Mc)[16])
{
  const int c = l & 31, k0 = 8 * (l >> 5);
  float a1[8], a2[8];
  {
    const float4 t0 = *(const float4*)(Xb + c * 32 + k0);
    const float4 t1 = *(const float4*)(Xb + c * 32 + k0 + 4);
    const float4 t2 = *(const float4*)(Xb + c * 32 + 16 + k0);
    const float4 t3 = *(const float4*)(Xb + c * 32 + 16 + k0 + 4);
    a1[0] = t0.x; a1[1] = t0.y; a1[2] = t0.z; a1[3] = t0.w;
    a1[4] = t1.x; a1[5] = t1.y; a1[6] = t1.z; a1[7] = t1.w;
    a2[0] = t2.x; a2[1] = t2.y; a2[2] = t2.z; a2[3] = t2.w;
    a2[4] = t3.x; a2[5] = t3.y; a2[6] = t3.z; a2[7] = t3.w;
  }
  Frag4 xf = split_frag(a1, a2);
  v16f acc;
#pragma unroll
  for (int g = 0; g < 16; ++g) acc[g] = 0.f;
  acc = prodAB(xf, tf, acc);              // H2 = X * T^T (full)
  float h2[16];
#pragma unroll
  for (int g = 0; g < 16; ++g) h2[g] = acc[g];
  Frag4 hf = frag_full(h2, lower);
  v16f wxv;
#pragma unroll
  for (int g = 0; g < 16; ++g) wxv[g] = 0.f;
  wxv = prodAB(tf, hf, wxv);              // WX = T X T^T (full)
  float Uc[16];
#pragma unroll
  for (int g = 0; g < 16; ++g) Uc[g] = fmaf(0.44444444f, (float)wxv[g], -1.1333333f * dsel[g]);
  Frag4 uf = frag_full(Uc, lower);
  // T2 = 2 U^2 - I  (B hi)
  v16f u2v;
#pragma unroll
  for (int g = 0; g < 16; ++g) u2v[g] = 0.f;
  u2v = prodAH(uf, uf, u2v);
  float T2c[16];
#pragma unroll
  for (int g = 0; g < 16; ++g) T2c[g] = fmaf(2.f, (float)u2v[g], -dsel[g]);
  Frag4 t2f = frag_full(T2c, lower);
  // W = T4(U) = 2 T2^2 - I  (B hi)
  v16f wvv;
#pragma unroll
  for (int g = 0; g < 16; ++g) wvv[g] = 0.f;
  wvv = prodAH(t2f, t2f, wvv);
  float Wc[16];
#pragma unroll
  for (int g = 0; g < 16; ++g) Wc[g] = fmaf(2.f, (float)wvv[g], -dsel[g]);
  Frag2 wf = frag_hi(Wc, lower);
  // T2(W) = 2 W^2 - I   (hi-only)
  v16f x2;
#pragma unroll
  for (int g = 0; g < 16; ++g) x2[g] = 0.f;
  x2 = prodHH(wf, wf, x2);
  float T2Wc[16];
#pragma unroll
  for (int g = 0; g < 16; ++g) T2Wc[g] = fmaf(2.f, (float)x2[g], -dsel[g]);
  Frag2 t2wf = frag_hi(T2Wc, lower);
  // T3(W) = 2 W T2(W) - W  (hi-only)
  v16f x3;
#pragma unroll
  for (int g = 0; g < 16; ++g) x3[g] = 0.f;
  x3 = prodHH(wf, t2wf, x3);
  float T3Wc[16];
#pragma unroll
  for (int g = 0; g < 16; ++g) T3Wc[g] = fmaf(2.f, (float)x3[g], -Wc[g]);
  Frag2 t3wf = frag_hi(T3Wc, lower);
  // G2, G3 fragments directly in packed f16 (gather linearity)
  Frag2 g3pk = combo4h(if2, wf, t2wf, t3wf,
                       0.11335902f, 1.1604296e-2f, 9.2604467e-4f, 8.6928673e-5f);
  Frag2 g2pk = combo4h(if2, wf, t2wf, t3wf,
                       -0.34555546f, -2.8889075e-2f, -2.2149252e-3f, -2.0372185e-4f);
  // qv = 0.5*(G1 - G3): direct fp32 combo (coeffs = (g1j-g3j)/2)
  v16f qv;
#pragma unroll
  for (int g = 0; g < 16; ++g)
    qv[g] = fmaf(2.4838830e-2f, Wc[g], fmaf(1.7330013e-3f, T2Wc[g],
             fmaf(1.5314434e-4f, T3Wc[g], 0.54041945f * dsel[g])));
  qv = prodAB2(t2f, g3pk, qv);            // + T2*G3
  float Qc[16];
#pragma unroll
  for (int g = 0; g < 16; ++g) Qc[g] = 2.f * (float)qv[g];
  Frag2 qfh = frag_hi(Qc, lower);         // B hi: U*Q loss ~6e-4, unamplified
  // r = G0 + U*Q + T2*G2
  v16f r;
#pragma unroll
  for (int g = 0; g < 16; ++g)
    r[g] = fmaf(-0.0648f, Wc[g], fmaf(-4.1990400e-3f, T2Wc[g],
            fmaf(-3.6279706e-4f, T3Wc[g], 0.62860866f * dsel[g])));
  r = prodAB2(uf, qfh, r);
  r = prodAB2(t2f, g2pk, r);
#pragma unroll
  for (int g = 0; g < 16; ++g) Mc[g] = r[g];
}

// W = Lw * expm(Fc) * Lw^T via PS (q=4, deg 10 Taylor), C-layout registers.
__device__ __forceinline__ void exp_apply(const float (&Fc)[16], const Frag4& tw,
                                          const float (&dsel)[16], bool lower,
                                          float (&Wc)[16])
{
  Frag4 ff = frag_full(Fc, lower);
  v16f p2;
#pragma unroll
  for (int g = 0; g < 16; ++g) p2[g] = 0.f;
  p2 = prodAB(ff, ff, p2);                // F2 (full: feeds 0.5 coeff + F3/F4)
  float F2c[16];
#pragma unroll
  for (int g = 0; g < 16; ++g) F2c[g] = p2[g];
  Frag4 f2f = frag_full(F2c, lower);
  v16f p3;
#pragma unroll
  for (int g = 0; g < 16; ++g) p3[g] = 0.f;
  p3 = prodAH(ff, f2f, p3);               // F3 (coeff <=1/6: B hi)
  float F3c[16];
#pragma unroll
  for (int g = 0; g < 16; ++g) F3c[g] = p3[g];
  v16f p4;
#pragma unroll
  for (int g = 0; g < 16; ++g) p4[g] = 0.f;
  p4 = prodAH(f2f, f2f, p4);              // F4 (coeff <=1/24: B hi)
  float F4c[16];
#pragma unroll
  for (int g = 0; g < 16; ++g) F4c[g] = p4[g];
  Frag2 f4fh = frag_hi(F4c, lower);       // F4 only ever used hi
  // P = I/8! + F/9! + F2/10!
  float Pc[16];
#pragma unroll
  for (int g = 0; g < 16; ++g)
    Pc[g] = fmaf(2.7557319e-7f, F2c[g], fmaf(2.7557319e-6f, Fc[g], 2.4801587e-5f * dsel[g]));
  Frag2 pf = frag_hi(Pc, lower);
  // Q = (I/4! + F/5! + F2/6! + F3/7!) + F4*P
  v16f q;
#pragma unroll
  for (int g = 0; g < 16; ++g)
    q[g] = fmaf(1.9841270e-4f, F3c[g],
            fmaf(1.3888889e-3f, F2c[g], fmaf(8.3333333e-3f, Fc[g], 4.1666667e-2f * dsel[g])));
  q = prodHH(f4fh, pf, q);
  float Qc[16];
#pragma unroll
  for (int g = 0; g < 16; ++g) Qc[g] = q[g];
  Frag2 qf = frag_hi(Qc, lower);
  // S = (I + F + F2/2 + F3/6) + F4*Q
  v16f s;
#pragma unroll
  for (int g = 0; g < 16; ++g)
    s[g] = fmaf(0.16666667f, F3c[g], fmaf(0.5f, F2c[g], Fc[g] + dsel[g]));
  s = prodHH(f4fh, qf, s);
  float Sc[16];
#pragma unroll
  for (int g = 0; g < 16; ++g) Sc[g] = s[g];
  // H2 = S * Lw^T (B hi: loss ~1.5e-3 under output quantization); W = Lw * H2
  Frag4 sf = frag_full(Sc, lower);
  v16f h;
#pragma unroll
  for (int g = 0; g < 16; ++g) h[g] = 0.f;
  h = prodAH(sf, tw, h);
  float h2[16];
#pragma unroll
  for (int g = 0; g < 16; ++g) h2[g] = h[g];
  Frag4 hf = frag_full(h2, lower);
  v16f wv;
#pragma unroll
  for (int g = 0; g < 16; ++g) wv[g] = 0.f;
  wv = prodAB(tw, hf, wv);
#pragma unroll
  for (int g = 0; g < 16; ++g) Wc[g] = wv[g];
}

// ---------------------------------------------------------------------------
// y <- A*y + ck*I  (single-wave helper kernels)
__device__ __forceinline__ void horner_step(const Frag4& af, float (&y)[16], float ck,
                                            const float (&dsel)[16], bool lower)
{
  float v1[8], v2[8];
  gather16(y, lower, v1, v2);
  Frag4 yf = split_frag(v1, v2);
  v16f a;
#pragma unroll
  for (int g = 0; g < 16; ++g) a[g] = ck * dsel[g];
  a = prodAB(af, yf, a);
#pragma unroll
  for (int g = 0; g < 16; ++g) y[g] = a[g];
}

__device__ __forceinline__ void load_Cmat(const float* __restrict__ g, float scale,
                                          int c, int rb, float (&Cc)[16])
{
#pragma unroll
  for (int q = 0; q < 4; ++q)
#pragma unroll
    for (int d = 0; d < 4; ++d)
      Cc[4 * q + d] = g[(8 * q + rb + d) * NM + c] * scale;
}

// Fused dual Cholesky (64 threads)
__device__ void chol32x2(float* A1, float* L1, float* A2, float* L2)
{
  const int t = threadIdx.x;
  for (int e = t; e < NM * PAD; e += 64) { L1[e] = 0.f; L2[e] = 0.f; }
  __syncthreads();
#pragma unroll 1
  for (int k = 0; k < NM; ++k) {
    const float r1 = rsqrtf(A1[k * PAD + k]);
    const float r2 = rsqrtf(A2[k * PAD + k]);
    if (t >= k && t < NM) {
      L1[t * PAD + k] = A1[t * PAD + k] * r1;
      L2[t * PAD + k] = A2[t * PAD + k] * r2;
    }
    __syncthreads();
    const int j = k + 1 + (t >> 1);
    if (j < NM) {
      const float l1 = L1[j * PAD + k], l2 = L2[j * PAD + k];
#pragma unroll 2
      for (int i = j + (t & 1); i < NM; i += 2) {
        A1[i * PAD + j] = fmaf(-L1[i * PAD + k], l1, A1[i * PAD + j]);
        A2[i * PAD + j] = fmaf(-L2[i * PAD + k], l2, A2[i * PAD + j]);
      }
    }
    __syncthreads();
  }
}

// ---------------------------------------------------------------------------
// P0: bm accumulation
__global__ __launch_bounds__(256) void k_bmsum(const float* __restrict__ X,
                                               float* __restrict__ bm_acc, int mats)
{
  const int t = threadIdx.x;
  const float* base = X + (size_t)blockIdx.x * mats * (NM * NM);
  float s0 = 0.f, s1 = 0.f, s2 = 0.f, s3 = 0.f;
  for (int b = 0; b < mats; ++b) {
    const float* Xb = base + (size_t)b * (NM * NM);
    s0 += Xb[t]; s1 += Xb[t + 256]; s2 += Xb[t + 512]; s3 += Xb[t + 768];
  }
  atomicAdd(&bm_acc[t], s0);       atomicAdd(&bm_acc[t + 256], s1);
  atomicAdd(&bm_acc[t + 512], s2); atomicAdd(&bm_acc[t + 768], s3);
}

// P0b: bm^{1/2}, bm^{-1/2}
__global__ void k_bmroot(const float* __restrict__ bm_acc, float inv_batch,
                         float* __restrict__ bm_sq_out, float* __restrict__ bm_isq_out)
{
  const int l = threadIdx.x;
  const bool lower = l < 32;
  const int c = l & 31, rb = 4 * (l >> 5);
  float dsel[16];
#pragma unroll
  for (int g = 0; g < 16; ++g) dsel[g] = ((g & 3) + 8 * (g >> 2) + rb == c) ? 1.f : 0.f;
  float bmc[16];
  load_Cmat(bm_acc, inv_batch, c, rb, bmc);
  float Ec[16];
#pragma unroll
  for (int g = 0; g < 16; ++g) Ec[g] = fmaf(0.5f, bmc[g], -dsel[g]);
  Frag4 ef = frag_full(Ec, lower);
  float y[16];
#pragma unroll
  for (int g = 0; g < 16; ++g) y[g] = fmaf(0.17619705f, Ec[g], -0.18547058f * dsel[g]);
  {
    const float bc[9] = {0.19638062f, -0.20947266f, 0.22558594f, -0.24609375f,
                         0.27343750f, -0.31250000f, 0.37500000f, -0.50000000f, 1.0f};
#pragma unroll
    for (int k = 0; k < 9; ++k) horner_step(ef, y, bc[k], dsel, lower);
  }
  const float is2 = 0.70710678f;
#pragma unroll
  for (int q = 0; q < 4; ++q)
    *(float4*)(bm_isq_out + c * NM + 8 * q + rb) =
        make_float4(y[4 * q] * is2, y[4 * q + 1] * is2,
                    y[4 * q + 2] * is2, y[4 * q + 3] * is2);
  float v1[8], v2[8];
  gather16(y, lower, v1, v2);
  Frag4 yf = split_frag(v1, v2);
  gather16(bmc, lower, v1, v2);
  Frag4 bf = split_frag(v1, v2);
  v16f a;
#pragma unroll
  for (int g = 0; g < 16; ++g) a[g] = 0.f;
  a = prodAB(bf, yf, a);
#pragma unroll
  for (int q = 0; q < 4; ++q)
    *(float4*)(bm_sq_out + c * NM + 8 * q + rb) =
        make_float4(a[4 * q] * is2, a[4 * q + 1] * is2,
                    a[4 * q + 2] * is2, a[4 * q + 3] * is2);
}

// P1: GT accumulation (contiguous per-wave chunks)
__global__ __launch_bounds__(256, 2) void k_karcher(const float* __restrict__ X,
                                                    const float* __restrict__ Sm,
                                                    float* __restrict__ gt_acc, int batch)
{
  __shared__ float red[WCNT][NM * PAD];
  const int tid = threadIdx.x, w = tid >> 6, l = tid & 63;
  const bool lower = l < 32;
  const int c = l & 31, rb = 4 * (l >> 5);
  float dsel[16];
#pragma unroll
  for (int g = 0; g < 16; ++g) dsel[g] = ((g & 3) + 8 * (g >> 2) + rb == c) ? 1.f : 0.f;
  const Frag2 if2 = frag_hi(dsel, lower);
  Frag4 tf = load_T(Sm, l);
  float gt[16];
#pragma unroll
  for (int g = 0; g < 16; ++g) gt[g] = 0.f;
  const int nw = gridDim.x * WCNT;
  const int wid = blockIdx.x * WCNT + w;
  const int qq = batch / nw, rr = batch - qq * nw;
  const int cnt = qq + (wid < rr ? 1 : 0);
  const int b0 = wid * qq + (wid < rr ? wid : rr);
#pragma unroll 1
  for (int ii = 0; ii < cnt; ++ii) {
    float Mc[16];
    log_chain(X + (size_t)(b0 + ii) * (NM * NM), tf, if2, dsel, lower, l, Mc);
#pragma unroll
    for (int g = 0; g < 16; ++g) gt[g] += Mc[g];
  }
#pragma unroll
  for (int q = 0; q < 4; ++q)
    *(float4*)(&red[w][c * PAD + 8 * q + rb]) =
        make_float4(gt[4 * q], gt[4 * q + 1], gt[4 * q + 2], gt[4 * q + 3]);
  __syncthreads();
  for (int e = tid; e < NM * NM; e += 256) {
    const int i = e >> 5, j = e & 31;
    float s = 0.f;
#pragma unroll
    for (int ww = 0; ww < WCNT; ++ww) s += red[ww][j * PAD + i];
    atomicAdd(&gt_acc[e], s);
  }
}

// P2: batch_mean = bm_sq expm(GT) bm_sq; Linv, Lw
__global__ void k_prep(const float* __restrict__ gt_acc, float inv_batch,
                       const float* __restrict__ bm_sq_g, const float* __restrict__ weight,
                       float* __restrict__ Linv_out, float* __restrict__ Lw_out)
{
  __shared__ float A1[NM * PAD], L1[NM * PAD], A2[NM * PAD], L2[NM * PAD];
  __shared__ float rd[NM];
  const int l = threadIdx.x;
  const bool lower = l < 32;
  const int c = l & 31, rb = 4 * (l >> 5);
  float dsel[16];
#pragma unroll
  for (int g = 0; g < 16; ++g) dsel[g] = ((g & 3) + 8 * (g >> 2) + rb == c) ? 1.f : 0.f;
  for (int e = l; e < NM * NM; e += 64) A2[(e >> 5) * PAD + (e & 31)] = weight[e];
  float Fc[16];
  load_Cmat(gt_acc, inv_batch, c, rb, Fc);
  Frag4 ff = frag_full(Fc, lower);
  float s[16];
#pragma unroll
  for (int g = 0; g < 16; ++g) s[g] = fmaf(2.7557319e-7f, Fc[g], 2.7557319e-6f * dsel[g]);
  {
    const float ec[9] = {2.4801587e-5f, 1.9841270e-4f, 1.3888889e-3f, 8.3333333e-3f,
                         4.1666667e-2f, 1.6666667e-1f, 0.5f, 1.f, 1.f};
#pragma unroll
    for (int k = 0; k < 9; ++k) horner_step(ff, s, ec[k], dsel, lower);
  }
  float bsc[16];
  load_Cmat(bm_sq_g, 1.f, c, rb, bsc);
  Frag4 sf = frag_full(s, lower);
  Frag4 bf = frag_full(bsc, lower);
  v16f h;
#pragma unroll
  for (int g = 0; g < 16; ++g) h[g] = 0.f;
  h = prodAB(sf, bf, h);
  float h2[16];
#pragma unroll
  for (int g = 0; g < 16; ++g) h2[g] = h[g];
  Frag4 hf = frag_full(h2, lower);
  v16f bmv;
#pragma unroll
  for (int g = 0; g < 16; ++g) bmv[g] = 0.f;
  bmv = prodAB(bf, hf, bmv);
#pragma unroll
  for (int q = 0; q < 4; ++q)
    *(float4*)(&A1[c * PAD + 8 * q + rb]) =
        make_float4(bmv[4 * q], bmv[4 * q + 1], bmv[4 * q + 2], bmv[4 * q + 3]);
  chol32x2(A1, L1, A2, L2);
  for (int e = l; e < NM * NM; e += 64) Lw_out[e] = L2[(e >> 5) * PAD + (e & 31)];
  if (l < NM) rd[l] = 1.f / L1[l * PAD + l];
  __syncthreads();
  if (l < NM) {
    float z[NM];
#pragma unroll
    for (int i = 0; i < NM; ++i) {
      float sv = (i == l) ? 1.f : 0.f;
#pragma unroll
      for (int j = 0; j < i; ++j) sv = fmaf(-L1[i * PAD + j], z[j], sv);
      z[i] = sv * rd[i];
    }
#pragma unroll
    for (int i = 0; i < NM; ++i) Linv_out[i * NM + l] = z[i];
  }
}

// P3: M = logm(Linv X Linv^T); var; optional M store (frag order)
__global__ __launch_bounds__(256, 2) void k_center(const float* __restrict__ X,
                                                   const float* __restrict__ Linv,
                                                   float* __restrict__ Mout,
                                                   float* __restrict__ var_acc,
                                                   int storeM, int batch)
{
  __shared__ float vred[WCNT];
  const int tid = threadIdx.x, w = tid >> 6, l = tid & 63;
  const bool lower = l < 32;
  const int c = l & 31, rb = 4 * (l >> 5);
  float dsel[16];
#pragma unroll
  for (int g = 0; g < 16; ++g) dsel[g] = ((g & 3) + 8 * (g >> 2) + rb == c) ? 1.f : 0.f;
  const Frag2 if2 = frag_hi(dsel, lower);
  Frag4 tf = load_T(Linv, l);
  float dist = 0.f;
  const int nw = gridDim.x * WCNT;
  const int wid = blockIdx.x * WCNT + w;
  const int qq = batch / nw, rr = batch - qq * nw;
  const int cnt = qq + (wid < rr ? 1 : 0);
  const int b0 = wid * qq + (wid < rr ? wid : rr);
#pragma unroll 1
  for (int ii = 0; ii < cnt; ++ii) {
    const int b = b0 + ii;
    float Mc[16];
    log_chain(X + (size_t)b * (NM * NM), tf, if2, dsel, lower, l, Mc);
    if (storeM) {
      float* Mb = Mout + (size_t)b * (NM * NM) + l * 16;
#pragma unroll
      for (int q = 0; q < 4; ++q)
        *(float4*)(Mb + 4 * q) =
            make_float4(Mc[4 * q], Mc[4 * q + 1], Mc[4 * q + 2], Mc[4 * q + 3]);
    }
#pragma unroll
    for (int g = 0; g < 16; ++g) dist = fmaf(Mc[g], Mc[g], dist);
  }
  for (int off = 32; off > 0; off >>= 1) dist += __shfl_down(dist, off);
  if (l == 0) vred[w] = dist;
  __syncthreads();
  if (tid == 0)
    atomicAdd(var_acc, vred[0] + vred[1] + vred[2] + vred[3]);
}

// P4: out = Lw expm(f*M) Lw^T (M from ws, frag order)
__global__ __launch_bounds__(256, 2) void k_scale(const float* __restrict__ Mi,
                                                  const float* __restrict__ Lw,
                                                  const float* __restrict__ shift,
                                                  const float* __restrict__ var_acc,
                                                  float* __restrict__ out, float invb,
                                                  int batch)
{
  const int tid = threadIdx.x, w = tid >> 6, l = tid & 63;
  const bool lower = l < 32;
  const int c = l & 31, rb = 4 * (l >> 5);
  float dsel[16];
#pragma unroll
  for (int g = 0; g < 16; ++g) dsel[g] = ((g & 3) + 8 * (g >> 2) + rb == c) ? 1.f : 0.f;
  Frag4 tw = load_T(Lw, l);
  const float fac = shift[0] / sqrtf(var_acc[0] * invb + 1e-5f);
  const int nw = gridDim.x * WCNT;
  const int wid = blockIdx.x * WCNT + w;
  const int qq = batch / nw, rr = batch - qq * nw;
  const int cnt = qq + (wid < rr ? 1 : 0);
  const int b0 = wid * qq + (wid < rr ? wid : rr);
#pragma unroll 1
  for (int ii = 0; ii < cnt; ++ii) {
    const int b = b0 + ii;
    const float* Mb = Mi + (size_t)b * (NM * NM) + l * 16;
    float Fc[16];
#pragma unroll
    for (int q = 0; q < 4; ++q) {
      const float4 m4 = *(const float4*)(Mb + 4 * q);
      Fc[4 * q] = fac * m4.x; Fc[4 * q + 1] = fac * m4.y;
      Fc[4 * q + 2] = fac * m4.z; Fc[4 * q + 3] = fac * m4.w;
    }
    float Wc[16];
    exp_apply(Fc, tw, dsel, lower, Wc);
    float* ob = out + (size_t)b * (NM * NM);
#pragma unroll
    for (int q = 0; q < 4; ++q)
      *(float4*)(ob + c * 32 + 8 * q + rb) =
          make_float4(Wc[4 * q], Wc[4 * q + 1], Wc[4 * q + 2], Wc[4 * q + 3]);
  }
}

// P4b fallback (ws too small): recompute log, then exp + output
__global__ __launch_bounds__(256, 2) void k_scale2(const float* __restrict__ X,
                                                   const float* __restrict__ Linv,
                                                   const float* __restrict__ Lw,
                                                   const float* __restrict__ shift,
                                                   const float* __restrict__ var_acc,
                                                   float* __restrict__ out, float invb,
                                                   int batch)
{
  const int tid = threadIdx.x, w = tid >> 6, l = tid & 63;
  const bool lower = l < 32;
  const int c = l & 31, rb = 4 * (l >> 5);
  float dsel[16];
#pragma unroll
  for (int g = 0; g < 16; ++g) dsel[g] = ((g & 3) + 8 * (g >> 2) + rb == c) ? 1.f : 0.f;
  const Frag2 if2 = frag_hi(dsel, lower);
  Frag4 tf = load_T(Linv, l);
  Frag4 tw = load_T(Lw, l);
  const float fac = shift[0] / sqrtf(var_acc[0] * invb + 1e-5f);
  const int nw = gridDim.x * WCNT;
  const int wid = blockIdx.x * WCNT + w;
  const int qq = batch / nw, rr = batch - qq * nw;
  const int cnt = qq + (wid < rr ? 1 : 0);
  const int b0 = wid * qq + (wid < rr ? wid : rr);
#pragma unroll 1
  for (int ii = 0; ii < cnt; ++ii) {
    const int b = b0 + ii;
    float Mc[16];
    log_chain(X + (size_t)b * (NM * NM), tf, if2, dsel, lower, l, Mc);
#pragma unroll
    for (int g = 0; g < 16; ++g) Mc[g] *= fac;
    float Wc[16];
    exp_apply(Mc, tw, dsel, lower, Wc);
    float* ob = out + (size_t)b * (NM * NM);
#pragma unroll
    for (int q = 0; q < 4; ++q)
      *(float4*)(ob + c * 32 + 8 * q + rb) =
          make_float4(Wc[4 * q], Wc[4 * q + 1], Wc[4 * q + 2], Wc[4 * q + 3]);
  }
}

// ---------------------------------------------------------------------------
extern "C" void kernel_launch(void* const* d_in, const int* in_sizes, int n_in,
                              void* d_out, int out_size, void* d_ws, size_t ws_size,
                              hipStream_t stream)
{
  const float* X = (const float*)d_in[0];
  const float* weight = (const float*)d_in[1];
  const float* shift = (const float*)d_in[2];
  float* out = (float*)d_out;
  float* W = (float*)d_ws;
  const int batch = in_sizes[0] / (NM * NM);          // 16384
  float* bm_acc = W;                                  // 1024
  float* gt_acc = W + 1024;                           // 1024
  float* var_acc = W + 2048;                          // 1 (+pad)
  float* bm_sq = W + 2304;                            // 1024
  float* bm_isq = W + 3328;                           // 1024
  float* Linv = W + 4352;                             // 1024 (row-major)
  float* Lw = W + 5376;                               // 1024 (row-major)
  float* M = W + 6400;                                // batch*1024
  const size_t needM = (size_t)(6400 + (size_t)batch * NM * NM) * sizeof(float);
  const int storeM = (ws_size >= needM) ? 1 : 0;
  const int GB = 1024;                                // 4 blocks/CU if regs allow
  const int GS = 512;                                 // bmsum grid
  const float invb = 1.f / (float)batch;

  hipMemsetAsync(W, 0, 2056 * sizeof(float), stream);

  hipLaunchKernelGGL(k_bmsum, dim3(GS), dim3(256), 0, stream, X, bm_acc, batch / GS);
  hipLaunchKernelGGL(k_bmroot, dim3(1), dim3(64), 0, stream, bm_acc, invb, bm_sq, bm_isq);
  hipLaunchKernelGGL(k_karcher, dim3(GB), dim3(256), 0, stream, X, bm_isq, gt_acc, batch);
  hipLaunchKernelGGL(k_prep, dim3(1), dim3(64), 0, stream, gt_acc, invb, bm_sq, weight, Linv, Lw);
  hipLaunchKernelGGL(k_center, dim3(GB), dim3(256), 0, stream, X, Linv, M, var_acc, storeM, batch);
  if (storeM)
    hipLaunchKernelGGL(k_scale, dim3(GB), dim3(256), 0, stream, M, Lw, shift, var_acc, out, invb, batch);
  else
    hipLaunchKernelGGL(k_scale2, dim3(GB), dim3(256), 0, stream, X, Linv, Lw, shift, var_acc, out, invb, batch);
}